// Round 1
// baseline (3904.694 us; speedup 1.0000x reference)
//
#include <hip/hip_runtime.h>
#include <math.h>

// Model constants
#define TB   4096      // B*S tokens
#define DD   1024      // model dim
#define NS   4         // streams
#define HH   16        // heads
#define HD   64        // head dim
#define RDIM 32        // rope dims
#define EE   8         // experts
#define KK   2         // topk
#define FF   512       // expert ffn
#define SS   2048      // seq len

__device__ inline float waveReduce(float v){
  #pragma unroll
  for(int off=32; off; off>>=1) v += __shfl_xor(v, off);
  return v;
}

// ---------------- rope table ----------------
__global__ void rope_table_kernel(float* __restrict__ cosT, float* __restrict__ sinT){
  int idx = blockIdx.x*256 + threadIdx.x;
  if(idx >= SS*16) return;
  int s = idx >> 4, i = idx & 15;
  float inv = powf(10000.0f, -(float)(2*i)/32.0f);
  float ang = (float)s * inv;
  cosT[idx] = cosf(ang);
  sinT[idx] = sinf(ang);
}

// ---------------- embedding gather ----------------
__global__ __launch_bounds__(256)
void embed_kernel(const float* __restrict__ embed, const int* __restrict__ ids,
                  float* __restrict__ emb){
  int t = blockIdx.x, tid = threadIdx.x;
  size_t src = (size_t)ids[t]*DD;
  size_t dst = (size_t)t*DD;
  #pragma unroll
  for(int j=0;j<4;j++){
    int d = tid + j*256;
    emb[dst+d] = embed[src+d];
  }
}

// ---------------- hyper-connection weights + collapse + rms*ln ----------------
// one block per token; wave w handles stream n=w. FINAL=true: only "pre" path
// (h_s/h_w), writes rms(out)*final_ln.
template<bool FINAL>
__global__ __launch_bounds__(256)
void hc_kernel(const float* __restrict__ xin, int nStride, int tStride,
               const float* __restrict__ sp, const float* __restrict__ wp,
               const float* __restrict__ so, const float* __restrict__ wpo,
               const float* __restrict__ sc, const float* __restrict__ wc,
               const float* __restrict__ ln,
               float* __restrict__ postO, float* __restrict__ combO,
               float* __restrict__ xfO)
{
  const int t = blockIdx.x;
  const int tid = threadIdx.x;
  const int w = tid >> 6, lane = tid & 63;
  __shared__ float spre[4];
  __shared__ float sA[16];
  __shared__ float sred[4];
  const float* xr = xin + (size_t)t*tStride + (size_t)w*nStride;
  float ss=0.f, dp=0.f, dpo=0.f, dc0=0.f, dc1=0.f, dc2=0.f, dc3=0.f;
  #pragma unroll
  for(int i=0;i<16;i++){
    int d = i*64 + lane;
    float v = xr[d];
    ss += v*v;
    dp += v*wp[d];
    if(!FINAL){
      dpo += v*wpo[d];
      float4 wc4 = ((const float4*)wc)[d];
      dc0 += v*wc4.x; dc1 += v*wc4.y; dc2 += v*wc4.z; dc3 += v*wc4.w;
    }
  }
  ss = waveReduce(ss); dp = waveReduce(dp);
  if(!FINAL){
    dpo = waveReduce(dpo);
    dc0 = waveReduce(dc0); dc1 = waveReduce(dc1);
    dc2 = waveReduce(dc2); dc3 = waveReduce(dc3);
  }
  if(lane==0){
    float r = 1.0f/sqrtf(ss*(1.0f/1024.0f) + 1e-6f);
    spre[w] = sp[w] + tanhf(r*dp);
    if(!FINAL){
      postO[t*4 + w] = so[w] + tanhf(r*dpo);
      sA[w*4+0] = sc[w*4+0] + tanhf(r*dc0);
      sA[w*4+1] = sc[w*4+1] + tanhf(r*dc1);
      sA[w*4+2] = sc[w*4+2] + tanhf(r*dc2);
      sA[w*4+3] = sc[w*4+3] + tanhf(r*dc3);
    }
  }
  __syncthreads();
  if(!FINAL && tid==0){
    float a[16];
    float mx = sA[0];
    #pragma unroll
    for(int i=1;i<16;i++) mx = fmaxf(mx, sA[i]);
    #pragma unroll
    for(int i=0;i<16;i++) a[i] = expf(sA[i]-mx);
    for(int it=0; it<20; it++){
      #pragma unroll
      for(int n=0;n<4;n++){
        float rs = a[n*4]+a[n*4+1]+a[n*4+2]+a[n*4+3] + 1e-9f;
        a[n*4]   /= rs; a[n*4+1] /= rs; a[n*4+2] /= rs; a[n*4+3] /= rs;
      }
      #pragma unroll
      for(int m=0;m<4;m++){
        float cs2 = a[m]+a[4+m]+a[8+m]+a[12+m] + 1e-9f;
        a[m] /= cs2; a[4+m] /= cs2; a[8+m] /= cs2; a[12+m] /= cs2;
      }
    }
    #pragma unroll
    for(int i=0;i<16;i++) combO[t*16+i] = a[i];
  }
  __syncthreads();
  // collapsed = sum_n pre[n]*x[n,:], then rms * ln
  float c[4]; float ssc = 0.f;
  const float p0 = spre[0], p1 = spre[1], p2 = spre[2], p3 = spre[3];
  const float* x0 = xin + (size_t)t*tStride;
  #pragma unroll
  for(int j=0;j<4;j++){
    int d = tid + j*256;
    float v = p0*x0[d] + p1*x0[nStride+d] + p2*x0[2*nStride+d] + p3*x0[3*nStride+d];
    c[j] = v; ssc += v*v;
  }
  ssc = waveReduce(ssc);
  if(lane==0) sred[w] = ssc;
  __syncthreads();
  float tot = sred[0]+sred[1]+sred[2]+sred[3];
  float rf = 1.0f/sqrtf(tot*(1.0f/1024.0f) + 1e-6f);
  #pragma unroll
  for(int j=0;j<4;j++){
    int d = tid + j*256;
    xfO[(size_t)t*DD + d] = c[j]*rf*ln[d];
  }
}

// ---------------- generic fp32 GEMM: C = [rowScale]*(A@B) [+C] ----------------
// A: MxK row-major, B: KxN row-major. 64x64 tile, BK=16, 256 thr, 4x4/thread.
template<int ACC>
__global__ __launch_bounds__(256)
void gemm_kernel(const float* __restrict__ A, const float* __restrict__ B,
                 float* __restrict__ C, int M, int N, int K,
                 const float* __restrict__ rowScale, int rsStride)
{
  __shared__ float As[16][64];
  __shared__ float Bs[16][64];
  const int tid = threadIdx.x;
  const int bm = blockIdx.y, bn = blockIdx.x;
  const int ty = tid>>4, tx = tid&15;
  float c[4][4];
  #pragma unroll
  for(int i=0;i<4;i++)
    #pragma unroll
    for(int j=0;j<4;j++) c[i][j]=0.f;
  const int arow  = bm*64 + (tid>>2);
  const int acol4 = (tid&3)*4;
  const int brow  = tid>>4;
  const int bcol  = bn*64 + (tid&15)*4;
  for(int kt=0; kt<K; kt+=16){
    float4 a4 = *(const float4*)&A[(size_t)arow*K + kt + acol4];
    float4 b4 = *(const float4*)&B[(size_t)(kt+brow)*N + bcol];
    As[acol4+0][tid>>2]=a4.x;
    As[acol4+1][tid>>2]=a4.y;
    As[acol4+2][tid>>2]=a4.z;
    As[acol4+3][tid>>2]=a4.w;
    *(float4*)&Bs[brow][(tid&15)*4] = b4;
    __syncthreads();
    #pragma unroll
    for(int kk=0;kk<16;kk++){
      float4 av = *(const float4*)&As[kk][ty*4];
      float4 bv = *(const float4*)&Bs[kk][tx*4];
      float aa[4]={av.x,av.y,av.z,av.w};
      float bb[4]={bv.x,bv.y,bv.z,bv.w};
      #pragma unroll
      for(int i=0;i<4;i++)
        #pragma unroll
        for(int j=0;j<4;j++)
          c[i][j] += aa[i]*bb[j];
    }
    __syncthreads();
  }
  #pragma unroll
  for(int i=0;i<4;i++){
    int row = bm*64 + ty*4 + i;
    float s = rowScale ? rowScale[(size_t)row*rsStride] : 1.0f;
    float4 outv;
    outv.x = s*c[i][0]; outv.y = s*c[i][1]; outv.z = s*c[i][2]; outv.w = s*c[i][3];
    float* cp = &C[(size_t)row*N + bn*64 + tx*4];
    if(ACC){
      float4 old = *(const float4*)cp;
      outv.x+=old.x; outv.y+=old.y; outv.z+=old.z; outv.w+=old.w;
    }
    *(float4*)cp = outv;
  }
}

// ---------------- rope on q and k (in place) ----------------
__global__ __launch_bounds__(256)
void rope_kernel(float* __restrict__ q, float* __restrict__ k,
                 const float* __restrict__ cosT, const float* __restrict__ sinT){
  int idx = blockIdx.x*256 + threadIdx.x;  // TB*HH*16
  int i  = idx & 15;
  int th = idx >> 4;            // t*HH + h
  int t  = th >> 4;
  int s  = t & (SS-1);
  size_t base = (size_t)th*HD;  // t*1024 + h*64
  float c = cosT[s*16+i], sn = sinT[s*16+i];
  float r1 = q[base+i], r2 = q[base+16+i];
  q[base+i]    = r1*c - r2*sn;
  q[base+16+i] = r2*c + r1*sn;
  r1 = k[base+i]; r2 = k[base+16+i];
  k[base+i]    = r1*c - r2*sn;
  k[base+16+i] = r2*c + r1*sn;
}

// ---------------- flash attention (causal) ----------------
// one thread per q row; block = 256 q rows of one (b,h); K/V tiles of 32 in LDS
__global__ __launch_bounds__(256)
void attn_kernel(const float* __restrict__ q, const float* __restrict__ k,
                 const float* __restrict__ v, float* __restrict__ ao)
{
  const int tid = threadIdx.x;
  const int qt = blockIdx.x;           // 0..7
  const int bh = blockIdx.y;           // 0..31
  const int b = bh >> 4, h = bh & 15;
  const int qi = qt*256 + tid;
  const size_t qoff = ((size_t)(b*SS + qi))*DD + h*HD;
  __shared__ float Ks[32][64];
  __shared__ float Vs[32][64];
  float4 qv[16];
  #pragma unroll
  for(int i=0;i<16;i++) qv[i] = *(const float4*)&q[qoff + i*4];
  float o[64];
  #pragma unroll
  for(int d=0; d<64; d++) o[d]=0.f;
  float m = -3.0e38f, l = 0.f;
  const int ntiles = qt*8 + 8;
  for(int kt=0; kt<ntiles; kt++){
    {
      const int row = tid>>3;
      const int col = (tid&7)*8;
      const size_t koff = ((size_t)(b*SS + kt*32 + row))*DD + h*HD + col;
      *(float4*)&Ks[row][col]   = *(const float4*)&k[koff];
      *(float4*)&Ks[row][col+4] = *(const float4*)&k[koff+4];
      *(float4*)&Vs[row][col]   = *(const float4*)&v[koff];
      *(float4*)&Vs[row][col+4] = *(const float4*)&v[koff+4];
    }
    __syncthreads();
    float sj[32];
    float tmax = -3.0e38f;
    #pragma unroll
    for(int j=0;j<32;j++){
      float acc = 0.f;
      #pragma unroll
      for(int i=0;i<16;i++){
        const float4 k4 = *(const float4*)&Ks[j][i*4];
        acc += qv[i].x*k4.x + qv[i].y*k4.y + qv[i].z*k4.z + qv[i].w*k4.w;
      }
      acc *= 0.125f;
      bool valid = (kt*32 + j) <= qi;
      sj[j] = valid ? acc : -3.0e38f;
      tmax = fmaxf(tmax, sj[j]);
    }
    if(tmax > -1.0e38f){
      float mnew = fmaxf(m, tmax);
      float corr = expf(m - mnew);
      m = mnew;
      l *= corr;
      #pragma unroll
      for(int d=0;d<64;d++) o[d]*=corr;
      #pragma unroll
      for(int j=0;j<32;j++){
        float p = expf(sj[j] - m);
        l += p;
        #pragma unroll
        for(int d=0;d<64;d++) o[d] += p*Vs[j][d];
      }
    }
    __syncthreads();
  }
  float invl = 1.0f/l;
  #pragma unroll
  for(int d=0;d<64;d++) ao[qoff + d] = o[d]*invl;
}

// ---------------- stream update 1 (x_in = broadcast emb) ----------------
__global__ __launch_bounds__(256)
void update1_kernel(const float* __restrict__ emb, const float* __restrict__ aop,
                    const float* __restrict__ post, const float* __restrict__ comb,
                    float* __restrict__ x)
{
  int t = blockIdx.x, tid = threadIdx.x;
  __shared__ float sp[4], scs[4];
  if(tid<4){
    sp[tid]  = post[t*4+tid];
    scs[tid] = comb[t*16+tid] + comb[t*16+4+tid] + comb[t*16+8+tid] + comb[t*16+12+tid];
  }
  __syncthreads();
  size_t base = (size_t)t*DD;
  #pragma unroll
  for(int j=0;j<4;j++){
    int d = tid + j*256;
    float e = emb[base+d], a = aop[base+d];
    size_t ob = (size_t)t*(NS*DD) + d;
    x[ob]        = sp[0]*a + scs[0]*e;
    x[ob+1024]   = sp[1]*a + scs[1]*e;
    x[ob+2048]   = sp[2]*a + scs[2]*e;
    x[ob+3072]   = sp[3]*a + scs[3]*e;
  }
}

// ---------------- stream update 2 (in place, general x) ----------------
__global__ __launch_bounds__(256)
void update2_kernel(float* __restrict__ x, const float* __restrict__ mlp,
                    const float* __restrict__ post, const float* __restrict__ comb)
{
  int t = blockIdx.x, tid = threadIdx.x;
  __shared__ float xs[4][1024];
  __shared__ float sp[4], scm[16];
  if(tid<4)  sp[tid]  = post[t*4+tid];
  if(tid<16) scm[tid] = comb[t*16+tid];
  size_t xb = (size_t)t*(NS*DD);
  #pragma unroll
  for(int n=0;n<4;n++)
    #pragma unroll
    for(int j=0;j<4;j++){
      int d = tid + j*256;
      xs[n][d] = x[xb + n*1024 + d];
    }
  __syncthreads();
  #pragma unroll
  for(int j=0;j<4;j++){
    int d = tid + j*256;
    float mv = mlp[(size_t)t*DD + d];
    float x0=xs[0][d], x1=xs[1][d], x2=xs[2][d], x3=xs[3][d];
    #pragma unroll
    for(int mI=0;mI<4;mI++){
      float vv = sp[mI]*mv + scm[mI]*x0 + scm[4+mI]*x1 + scm[8+mI]*x2 + scm[12+mI]*x3;
      x[xb + mI*1024 + d] = vv;
    }
  }
}

// ---------------- gate: combine weights ----------------
__global__ __launch_bounds__(256)
void gate_kernel(const float* __restrict__ xf, const float* __restrict__ gate_w,
                 const int* __restrict__ ids, const int* __restrict__ tid2eid,
                 float* __restrict__ combine)
{
  int t = blockIdx.x, tid = threadIdx.x;
  int w = tid>>6, lane = tid&63;
  __shared__ float sg[8];
  const float* xr = xf + (size_t)t*DD;
  const float* g0 = gate_w + (size_t)(w*2)*DD;
  const float* g1 = g0 + DD;
  float d0=0.f, d1=0.f;
  #pragma unroll
  for(int i=0;i<16;i++){
    int d = i*64+lane;
    float vv = xr[d];
    d0 += vv*g0[d]; d1 += vv*g1[d];
  }
  d0 = waveReduce(d0); d1 = waveReduce(d1);
  if(lane==0){ sg[w*2]=d0; sg[w*2+1]=d1; }
  __syncthreads();
  if(tid==0){
    float sc[8];
    #pragma unroll
    for(int e=0;e<8;e++){
      float xv = sg[e];
      float spv = fmaxf(xv,0.f) + log1pf(expf(-fabsf(xv)));
      sc[e] = sqrtf(spv);
    }
    int tok = ids[t];
    int i0 = tid2eid[tok*2], i1 = tid2eid[tok*2+1];
    float w0 = sc[i0], w1 = sc[i1];
    float den = w0 + w1 + 1e-20f;
    w0 = w0/den*2.5f; w1 = w1/den*2.5f;
    float cb[8];
    #pragma unroll
    for(int e=0;e<8;e++) cb[e]=0.f;
    cb[i0]+=w0; cb[i1]+=w1;
    #pragma unroll
    for(int e=0;e<8;e++) combine[t*8+e]=cb[e];
  }
}

// ---------------- silu(h1)*h3 -> h1 ----------------
__global__ __launch_bounds__(256)
void silu_mul_kernel(float* __restrict__ h1, const float* __restrict__ h3, int n4){
  int idx = blockIdx.x*256 + threadIdx.x;
  if(idx >= n4) return;
  float4 a = ((const float4*)h1)[idx];
  float4 b = ((const float4*)h3)[idx];
  float4 r;
  r.x = (a.x/(1.f+expf(-a.x)))*b.x;
  r.y = (a.y/(1.f+expf(-a.y)))*b.y;
  r.z = (a.z/(1.f+expf(-a.z)))*b.z;
  r.w = (a.w/(1.f+expf(-a.w)))*b.w;
  ((float4*)h1)[idx] = r;
}

extern "C" void kernel_launch(void* const* d_in, const int* in_sizes, int n_in,
                              void* d_out, int out_size, void* d_ws, size_t ws_size,
                              hipStream_t stream)
{
  const float* embed   = (const float*)d_in[0];
  const float* wq      = (const float*)d_in[1];
  const float* wk      = (const float*)d_in[2];
  const float* wv      = (const float*)d_in[3];
  const float* wo      = (const float*)d_in[4];
  const float* in_ln   = (const float*)d_in[5];
  const float* post_ln = (const float*)d_in[6];
  const float* final_ln= (const float*)d_in[7];
  const float* a_sp = (const float*)d_in[8];
  const float* a_wp = (const float*)d_in[9];
  const float* a_so = (const float*)d_in[10];
  const float* a_wo = (const float*)d_in[11];
  const float* a_sc = (const float*)d_in[12];
  const float* a_wc = (const float*)d_in[13];
  const float* f_sp = (const float*)d_in[14];
  const float* f_wp = (const float*)d_in[15];
  const float* f_so = (const float*)d_in[16];
  const float* f_wo = (const float*)d_in[17];
  const float* f_sc = (const float*)d_in[18];
  const float* f_wc = (const float*)d_in[19];
  const float* h_s  = (const float*)d_in[20];
  const float* h_w  = (const float*)d_in[21];
  const float* gate_w = (const float*)d_in[22];
  const float* e_w1 = (const float*)d_in[23];
  const float* e_w3 = (const float*)d_in[24];
  const float* e_w2 = (const float*)d_in[25];
  const float* s_w1 = (const float*)d_in[26];
  const float* s_w3 = (const float*)d_in[27];
  const float* s_w2 = (const float*)d_in[28];
  const int* input_ids = (const int*)d_in[29];
  const int* tid2eid   = (const int*)d_in[30];
  float* out = (float*)d_out;

  float* ws = (float*)d_ws;
  size_t off = 0;
  auto alloc = [&](size_t n){ float* p = ws + off; off += n; return p; };
  float* x     = alloc((size_t)TB*NS*DD);   // 16.8M
  float* emb   = alloc((size_t)TB*DD);
  float* xf    = alloc((size_t)TB*DD);
  float* q     = alloc((size_t)TB*DD);
  float* kbuf  = alloc((size_t)TB*DD);
  float* vbuf  = alloc((size_t)TB*DD);
  float* ao    = alloc((size_t)TB*DD);
  float* aop   = alloc((size_t)TB*DD);
  float* post1 = alloc((size_t)TB*NS);
  float* comb1 = alloc((size_t)TB*NS*NS);
  float* post2 = alloc((size_t)TB*NS);
  float* comb2 = alloc((size_t)TB*NS*NS);
  float* combine = alloc((size_t)TB*EE);
  float* cosT  = alloc((size_t)SS*16);
  float* sinT  = alloc((size_t)SS*16);
  if(off*sizeof(float) > ws_size) return;   // ws too small -> fail validation visibly
  // aliases (dead after attention)
  float* h1  = q;      // TB*FF = 2.1M <= 4.19M
  float* h3  = vbuf;
  float* mlp = kbuf;

  rope_table_kernel<<<(SS*16+255)/256, 256, 0, stream>>>(cosT, sinT);
  embed_kernel<<<TB, 256, 0, stream>>>(embed, input_ids, emb);

  // ---- layer part 1: attention branch ----
  hc_kernel<false><<<TB, 256, 0, stream>>>(emb, 0, DD,
      a_sp, a_wp, a_so, a_wo, a_sc, a_wc, in_ln, post1, comb1, xf);
  gemm_kernel<0><<<dim3(16,64), 256, 0, stream>>>(xf, wq, q,    TB, 1024, 1024, nullptr, 0);
  gemm_kernel<0><<<dim3(16,64), 256, 0, stream>>>(xf, wk, kbuf, TB, 1024, 1024, nullptr, 0);
  gemm_kernel<0><<<dim3(16,64), 256, 0, stream>>>(xf, wv, vbuf, TB, 1024, 1024, nullptr, 0);
  rope_kernel<<<(TB*HH*16)/256, 256, 0, stream>>>(q, kbuf, cosT, sinT);
  attn_kernel<<<dim3(SS/256, 2*HH), 256, 0, stream>>>(q, kbuf, vbuf, ao);
  gemm_kernel<0><<<dim3(16,64), 256, 0, stream>>>(ao, wo, aop, TB, 1024, 1024, nullptr, 0);
  update1_kernel<<<TB, 256, 0, stream>>>(emb, aop, post1, comb1, x);

  // ---- layer part 2: MoE branch ----
  hc_kernel<false><<<TB, 256, 0, stream>>>(x, DD, NS*DD,
      f_sp, f_wp, f_so, f_wo, f_sc, f_wc, post_ln, post2, comb2, xf);
  gate_kernel<<<TB, 256, 0, stream>>>(xf, gate_w, input_ids, tid2eid, combine);
  for(int e=0;e<EE;e++){
    const float* w1e = e_w1 + (size_t)e*DD*FF;
    const float* w3e = e_w3 + (size_t)e*DD*FF;
    const float* w2e = e_w2 + (size_t)e*FF*DD;
    gemm_kernel<0><<<dim3(8,64), 256, 0, stream>>>(xf, w1e, h1, TB, FF, DD, nullptr, 0);
    gemm_kernel<0><<<dim3(8,64), 256, 0, stream>>>(xf, w3e, h3, TB, FF, DD, nullptr, 0);
    silu_mul_kernel<<<(TB*FF/4+255)/256, 256, 0, stream>>>(h1, h3, TB*FF/4);
    if(e==0)
      gemm_kernel<0><<<dim3(16,64), 256, 0, stream>>>(h1, w2e, mlp, TB, DD, FF, combine+e, EE);
    else
      gemm_kernel<1><<<dim3(16,64), 256, 0, stream>>>(h1, w2e, mlp, TB, DD, FF, combine+e, EE);
  }
  // shared expert
  gemm_kernel<0><<<dim3(8,64), 256, 0, stream>>>(xf, s_w1, h1, TB, FF, DD, nullptr, 0);
  gemm_kernel<0><<<dim3(8,64), 256, 0, stream>>>(xf, s_w3, h3, TB, FF, DD, nullptr, 0);
  silu_mul_kernel<<<(TB*FF/4+255)/256, 256, 0, stream>>>(h1, h3, TB*FF/4);
  gemm_kernel<1><<<dim3(16,64), 256, 0, stream>>>(h1, s_w2, mlp, TB, DD, FF, nullptr, 0);
  update2_kernel<<<TB, 256, 0, stream>>>(x, mlp, post2, comb2);

  // ---- final head ----
  hc_kernel<true><<<TB, 256, 0, stream>>>(x, DD, NS*DD,
      h_s, h_w, nullptr, nullptr, nullptr, nullptr, final_ln,
      nullptr, nullptr, out);
}